// Round 6
// baseline (117.779 us; speedup 1.0000x reference)
//
#include <hip/hip_runtime.h>

// TwoTwoNet: rank-2 recurrence collapse, round 5.
// Key change vs R4: the per-lane tables were NOT register-resident
// (VGPR_Count=64 < 80 table floats) -> per-step L1/scratch re-reads dominated.
// Fix: pin every table value with an opaque asm ("+v") so the compiler cannot
// rematerialize from memory; inner loop uses explicit v_pk_fma_f32/v_pk_mul_f32.
// Tables: d, e, g1=w00*m*d+w01*m*e, g2=w10*m*d+w11*m*e, wo=m*decoder
// Per step: m' = med3(d + (beta/au)*e, -|1/au|, +|1/au|); reduce 3 dots
// (g1 -> q1, g2 -> q2, wo -> sigma_o) via DPP to lane 63, readlane broadcast.

typedef float f32x2 __attribute__((ext_vector_type(2)));

constexpr int Bc = 256;
constexpr int Tc = 512;
constexpr int CH = Tc / 64;   // 8 chunks of 64 steps

template <int CTRL, int RMASK>
__device__ __forceinline__ float dpp_add(float v) {
    int t = __builtin_amdgcn_update_dpp(0, __float_as_int(v), CTRL, RMASK, 0xf, true);
    return v + __int_as_float(t);
}

// Full 64-lane sum; result valid in lane 63.
__device__ __forceinline__ float wave_sum63(float v) {
    v = dpp_add<0x111, 0xf>(v);  // row_shr:1
    v = dpp_add<0x112, 0xf>(v);  // row_shr:2
    v = dpp_add<0x114, 0xf>(v);  // row_shr:4
    v = dpp_add<0x118, 0xf>(v);  // row_shr:8
    v = dpp_add<0x142, 0xa>(v);  // row_bcast:15 -> rows 1,3
    v = dpp_add<0x143, 0xc>(v);  // row_bcast:31 -> rows 2,3
    return v;
}

__device__ __forceinline__ float readlane_f(float v, int l) {
    return __int_as_float(__builtin_amdgcn_readlane(__float_as_int(v), l));
}

__device__ __forceinline__ f32x2 pk_fma(f32x2 a, f32x2 b, f32x2 c) {
    f32x2 d;
    asm("v_pk_fma_f32 %0, %1, %2, %3" : "=v"(d) : "v"(a), "v"(b), "v"(c));
    return d;
}

__device__ __forceinline__ f32x2 pk_mul(f32x2 a, f32x2 b) {
    f32x2 d;
    asm("v_pk_mul_f32 %0, %1, %2" : "=v"(d) : "v"(a), "v"(b));
    return d;
}

#define DECL_TBL(i) f32x2 d2_##i, e2_##i, g1_##i, g2_##i, wo_##i

#define INIT_TBL(i) do { \
    _Pragma("unroll") \
    for (int h = 0; h < 2; ++h) { \
        const int c = lane + 64 * (2 * (i) + h); \
        const float dv   = dec_orth[c]; \
        const float ev   = enc_orth[c]; \
        const float mv   = mask[c]; \
        const float encv = encoder[c]; \
        const float decv = decoder[c]; \
        const float s0v  = state0[c]; \
        const float mdv = mv * dv, mev = mv * ev; \
        d2_##i[h]  = dv;  e2_##i[h]  = ev; \
        g1_##i[h] = fmaf(w00, mdv, w01 * mev); \
        g2_##i[h] = fmaf(w10, mdv, w11 * mev); \
        wo_##i[h] = mv * decv; \
        s0d += s0v * dv;  s0e += s0v * ev; \
        kd = fmaf(mv * encv, dv, kd); \
        ke = fmaf(mv * encv, ev, ke); \
    } \
} while (0)

// Opaque pin: value becomes an asm result the compiler cannot rematerialize
// from its originating load -> must stay in VGPRs across the loop.
#define PIN_TBL(i) \
    asm volatile("" : "+v"(d2_##i), "+v"(e2_##i), "+v"(g1_##i), "+v"(g2_##i), "+v"(wo_##i))

#define ACC_PAIR(i, OP1, OP2, OP3) do { \
    f32x2 tt = pk_fma(r2, e2_##i, d2_##i); \
    f32x2 mm; \
    mm.x = __builtin_amdgcn_fmed3f(tt.x, nb, bb); \
    mm.y = __builtin_amdgcn_fmed3f(tt.y, nb, bb); \
    OP1; OP2; OP3; \
} while (0)

__global__ __launch_bounds__(64, 1) void twotwonet_kernel(
    const float* __restrict__ x,        // [B, T]
    const float* __restrict__ state0,   // [n]
    const float* __restrict__ mask,     // [n]
    const float* __restrict__ w,        // [2,2]
    const float* __restrict__ dec_orth, // [n]
    const float* __restrict__ enc_orth, // [n]
    const float* __restrict__ decoder,  // [n]
    const float* __restrict__ encoder,  // [n]
    float* __restrict__ out)            // [B, T]
{
    const int b    = blockIdx.x;
    const int lane = threadIdx.x;   // 0..63

    const float w00 = w[0], w01 = w[1], w10 = w[2], w11 = w[3];

    DECL_TBL(0); DECL_TBL(1); DECL_TBL(2); DECL_TBL(3);
    DECL_TBL(4); DECL_TBL(5); DECL_TBL(6); DECL_TBL(7);

    float s0d = 0.f, s0e = 0.f, kd = 0.f, ke = 0.f;
    INIT_TBL(0); INIT_TBL(1); INIT_TBL(2); INIT_TBL(3);
    INIT_TBL(4); INIT_TBL(5); INIT_TBL(6); INIT_TBL(7);

    PIN_TBL(0); PIN_TBL(1); PIN_TBL(2); PIN_TBL(3);
    PIN_TBL(4); PIN_TBL(5); PIN_TBL(6); PIN_TBL(7);

    // cold-path init reduce (runs once)
#pragma unroll
    for (int m = 32; m >= 1; m >>= 1) {
        s0d += __shfl_xor(s0d, m, 64);
        s0e += __shfl_xor(s0e, m, 64);
        kd  += __shfl_xor(kd, m, 64);
        ke  += __shfl_xor(ke, m, 64);
    }

    const float A1 = fmaf(w00, kd, w01 * ke);   // x-coupling for alpha
    const float A2 = fmaf(w10, kd, w11 * ke);   // x-coupling for beta

    // Preload this batch's entire x row: 8 regs, 64 steps each. Pin them too.
    const float* xrow = x + (size_t)b * Tc;
    float xr[CH];
#pragma unroll
    for (int c = 0; c < CH; ++c) xr[c] = xrow[lane + 64 * c];
    asm volatile("" : "+v"(xr[0]), "+v"(xr[1]), "+v"(xr[2]), "+v"(xr[3]),
                      "+v"(xr[4]), "+v"(xr[5]), "+v"(xr[6]), "+v"(xr[7]));

    // Carried state: alpha = au*q1 + x*A1, beta = au*q2 + x*A2.
    float au = 1.0f;
    float q1 = fmaf(w00, s0d, w01 * s0e);
    float q2 = fmaf(w10, s0d, w11 * s0e);

#pragma unroll
    for (int c = 0; c < CH; ++c) {
        float obuf = 0.f;
#pragma unroll 2
        for (int t2 = 0; t2 < 64; ++t2) {
            const float xs = readlane_f(xr[c], t2);

            const float alpha = fmaf(au, q1, xs * A1);
            const float beta  = fmaf(au, q2, xs * A2);

            const float aun = copysignf(fmaxf(fabsf(alpha), 1e-20f), alpha);
            const float inv = __builtin_amdgcn_rcpf(aun);
            const float r   = beta * inv;
            const float bb  = fabsf(inv);
            const float nb  = -bb;
            const f32x2 r2  = {r, r};

            f32x2 a1a, a1b, a2a, a2b, aoa, aob;
            // group A: j=0..3 (first acc = mul), group B: j=4..7
            ACC_PAIR(0, a1a = pk_mul(mm, g1_0), a2a = pk_mul(mm, g2_0), aoa = pk_mul(mm, wo_0));
            ACC_PAIR(1, a1a = pk_fma(mm, g1_1, a1a), a2a = pk_fma(mm, g2_1, a2a), aoa = pk_fma(mm, wo_1, aoa));
            ACC_PAIR(2, a1a = pk_fma(mm, g1_2, a1a), a2a = pk_fma(mm, g2_2, a2a), aoa = pk_fma(mm, wo_2, aoa));
            ACC_PAIR(3, a1a = pk_fma(mm, g1_3, a1a), a2a = pk_fma(mm, g2_3, a2a), aoa = pk_fma(mm, wo_3, aoa));
            ACC_PAIR(4, a1b = pk_mul(mm, g1_4), a2b = pk_mul(mm, g2_4), aob = pk_mul(mm, wo_4));
            ACC_PAIR(5, a1b = pk_fma(mm, g1_5, a1b), a2b = pk_fma(mm, g2_5, a2b), aob = pk_fma(mm, wo_5, aob));
            ACC_PAIR(6, a1b = pk_fma(mm, g1_6, a1b), a2b = pk_fma(mm, g2_6, a2b), aob = pk_fma(mm, wo_6, aob));
            ACC_PAIR(7, a1b = pk_fma(mm, g1_7, a1b), a2b = pk_fma(mm, g2_7, a2b), aob = pk_fma(mm, wo_7, aob));

            const f32x2 s1v = a1a + a1b;
            const f32x2 s2v = a2a + a2b;
            const f32x2 sov = aoa + aob;
            float h1 = s1v.x + s1v.y;
            float h2 = s2v.x + s2v.y;
            float ho = sov.x + sov.y;

            // three independent DPP chains interleave to hide dep latency
            h1 = wave_sum63(h1);
            h2 = wave_sum63(h2);
            ho = wave_sum63(ho);

            q1 = readlane_f(h1, 63);       // = w00*sigma_d + w01*sigma_e
            q2 = readlane_f(h2, 63);
            const float so = readlane_f(ho, 63);
            au = aun;

            const float ov = aun * so;     // out_t = au * sigma_o
            obuf = (t2 == lane) ? ov : obuf;
        }
        out[(size_t)b * Tc + 64 * c + lane] = obuf;
    }
}

extern "C" void kernel_launch(void* const* d_in, const int* in_sizes, int n_in,
                              void* d_out, int out_size, void* d_ws, size_t ws_size,
                              hipStream_t stream) {
    const float* x        = (const float*)d_in[0];
    const float* state0   = (const float*)d_in[1];
    const float* mask     = (const float*)d_in[2];
    const float* w        = (const float*)d_in[3];
    const float* dec_orth = (const float*)d_in[4];
    const float* enc_orth = (const float*)d_in[5];
    const float* decoder  = (const float*)d_in[6];
    const float* encoder  = (const float*)d_in[7];
    float* out = (float*)d_out;

    twotwonet_kernel<<<dim3(Bc), dim3(64), 0, stream>>>(
        x, state0, mask, w, dec_orth, enc_orth, decoder, encoder, out);
}

// Round 7
// 99.387 us; speedup vs baseline: 1.1851x; 1.1851x over previous
//
#include <hip/hip_runtime.h>

// TwoTwoNet: rank-2 recurrence collapse, round 6.
// R5 evidence: WRITE==output exactly, FETCH==inputs exactly -> no scratch HBM
// traffic; VGPR_Count pinned at 64 means the allocator kept arch-VGPRs at an
// occupancy-heuristic cap and serviced the 80-float tables via AGPR-side
// copies (unified file) -> ~60 extra issued instrs/step. Fixes:
//   1) amdgpu_waves_per_eu(1,1): occupancy target = 1 wave/EU -> full VGPR
//      budget (VGPR_Count is the verification signal).
//   2) No asm pins / asm pk ops (they force copies at constraint points).
//   3) One asm block for the wave reduce: 18x fused v_add_f32_dpp, 3 chains
//      interleaved 3-apart (covers the 2-wait-state DPP hazard exactly),
//      plus 3x v_readlane_b32 -> SGPRs in-block.
// Math (unchanged, verified R3-R5): s = mask*clip(alpha*dec+beta*enc);
// carry (au,q1,q2); inner m = med3(d + (beta/au)*e, -|1/au|, +|1/au|);
// tables g1 = w00*m*d+w01*m*e, g2 = w10*m*d+w11*m*e fold W into the reduce.

typedef float f32x2 __attribute__((ext_vector_type(2)));

constexpr int Bc = 256;
constexpr int Tc = 512;
constexpr int CH = Tc / 64;   // 8 chunks of 64 steps

__device__ __forceinline__ float readlane_f(float v, int l) {
    return __int_as_float(__builtin_amdgcn_readlane(__float_as_int(v), l));
}

// 3 interleaved 64-lane sums via DPP; totals land in lane 63, read out to SGPRs.
// Interleave distance 3 satisfies the VALU->DPP 2-wait-state hazard; s_nop 1
// covers the entry hazard (accumulators written by the immediately preceding
// VALU adds).
#define WAVE_REDUCE3_READ(h1, h2, h3, s1, s2, s3)                                                  \
    asm("s_nop 1\n\t"                                                                              \
        "v_add_f32_dpp %[a], %[a], %[a] row_shr:1 row_mask:0xf bank_mask:0xf bound_ctrl:1\n\t"     \
        "v_add_f32_dpp %[b], %[b], %[b] row_shr:1 row_mask:0xf bank_mask:0xf bound_ctrl:1\n\t"     \
        "v_add_f32_dpp %[c], %[c], %[c] row_shr:1 row_mask:0xf bank_mask:0xf bound_ctrl:1\n\t"     \
        "v_add_f32_dpp %[a], %[a], %[a] row_shr:2 row_mask:0xf bank_mask:0xf bound_ctrl:1\n\t"     \
        "v_add_f32_dpp %[b], %[b], %[b] row_shr:2 row_mask:0xf bank_mask:0xf bound_ctrl:1\n\t"     \
        "v_add_f32_dpp %[c], %[c], %[c] row_shr:2 row_mask:0xf bank_mask:0xf bound_ctrl:1\n\t"     \
        "v_add_f32_dpp %[a], %[a], %[a] row_shr:4 row_mask:0xf bank_mask:0xf bound_ctrl:1\n\t"     \
        "v_add_f32_dpp %[b], %[b], %[b] row_shr:4 row_mask:0xf bank_mask:0xf bound_ctrl:1\n\t"     \
        "v_add_f32_dpp %[c], %[c], %[c] row_shr:4 row_mask:0xf bank_mask:0xf bound_ctrl:1\n\t"     \
        "v_add_f32_dpp %[a], %[a], %[a] row_shr:8 row_mask:0xf bank_mask:0xf bound_ctrl:1\n\t"     \
        "v_add_f32_dpp %[b], %[b], %[b] row_shr:8 row_mask:0xf bank_mask:0xf bound_ctrl:1\n\t"     \
        "v_add_f32_dpp %[c], %[c], %[c] row_shr:8 row_mask:0xf bank_mask:0xf bound_ctrl:1\n\t"     \
        "v_add_f32_dpp %[a], %[a], %[a] row_bcast:15 row_mask:0xa bank_mask:0xf\n\t"               \
        "v_add_f32_dpp %[b], %[b], %[b] row_bcast:15 row_mask:0xa bank_mask:0xf\n\t"               \
        "v_add_f32_dpp %[c], %[c], %[c] row_bcast:15 row_mask:0xa bank_mask:0xf\n\t"               \
        "v_add_f32_dpp %[a], %[a], %[a] row_bcast:31 row_mask:0xc bank_mask:0xf\n\t"               \
        "v_add_f32_dpp %[b], %[b], %[b] row_bcast:31 row_mask:0xc bank_mask:0xf\n\t"               \
        "v_add_f32_dpp %[c], %[c], %[c] row_bcast:31 row_mask:0xc bank_mask:0xf\n\t"               \
        "v_readlane_b32 %[x], %[a], 63\n\t"                                                        \
        "v_readlane_b32 %[y], %[b], 63\n\t"                                                        \
        "v_readlane_b32 %[z], %[c], 63"                                                            \
        : [a] "+v"(h1), [b] "+v"(h2), [c] "+v"(h3),                                                \
          [x] "=s"(s1), [y] "=s"(s2), [z] "=s"(s3))

#define DECL_TBL(i) f32x2 d2_##i, e2_##i, g1_##i, g2_##i, wo_##i

#define INIT_TBL(i) do { \
    _Pragma("unroll") \
    for (int h = 0; h < 2; ++h) { \
        const int c = lane + 64 * (2 * (i) + h); \
        const float dv   = dec_orth[c]; \
        const float ev   = enc_orth[c]; \
        const float mv   = mask[c]; \
        const float encv = encoder[c]; \
        const float decv = decoder[c]; \
        const float s0v  = state0[c]; \
        const float mdv = mv * dv, mev = mv * ev; \
        d2_##i[h]  = dv;  e2_##i[h]  = ev; \
        g1_##i[h] = fmaf(w00, mdv, w01 * mev); \
        g2_##i[h] = fmaf(w10, mdv, w11 * mev); \
        wo_##i[h] = mv * decv; \
        s0d += s0v * dv;  s0e += s0v * ev; \
        kd = fmaf(mv * encv, dv, kd); \
        ke = fmaf(mv * encv, ev, ke); \
    } \
} while (0)

#define ACC_J(i, A1V, A2V, AOV) do { \
    f32x2 tt = r2 * e2_##i + d2_##i;                 /* v_pk_fma_f32 */ \
    f32x2 mm; \
    mm.x = __builtin_amdgcn_fmed3f(tt.x, nb, bb); \
    mm.y = __builtin_amdgcn_fmed3f(tt.y, nb, bb); \
    A1V += mm * g1_##i; \
    A2V += mm * g2_##i; \
    AOV += mm * wo_##i; \
} while (0)

__global__ __attribute__((amdgpu_waves_per_eu(1, 1))) __launch_bounds__(64)
void twotwonet_kernel(
    const float* __restrict__ x,        // [B, T]
    const float* __restrict__ state0,   // [n]
    const float* __restrict__ mask,     // [n]
    const float* __restrict__ w,        // [2,2]
    const float* __restrict__ dec_orth, // [n]
    const float* __restrict__ enc_orth, // [n]
    const float* __restrict__ decoder,  // [n]
    const float* __restrict__ encoder,  // [n]
    float* __restrict__ out)            // [B, T]
{
    const int b    = blockIdx.x;
    const int lane = threadIdx.x;   // 0..63

    const float w00 = w[0], w01 = w[1], w10 = w[2], w11 = w[3];

    DECL_TBL(0); DECL_TBL(1); DECL_TBL(2); DECL_TBL(3);
    DECL_TBL(4); DECL_TBL(5); DECL_TBL(6); DECL_TBL(7);

    float s0d = 0.f, s0e = 0.f, kd = 0.f, ke = 0.f;
    INIT_TBL(0); INIT_TBL(1); INIT_TBL(2); INIT_TBL(3);
    INIT_TBL(4); INIT_TBL(5); INIT_TBL(6); INIT_TBL(7);

    // cold-path init reduce (runs once)
#pragma unroll
    for (int m = 32; m >= 1; m >>= 1) {
        s0d += __shfl_xor(s0d, m, 64);
        s0e += __shfl_xor(s0e, m, 64);
        kd  += __shfl_xor(kd, m, 64);
        ke  += __shfl_xor(ke, m, 64);
    }

    const float A1 = fmaf(w00, kd, w01 * ke);   // x-coupling for alpha
    const float A2 = fmaf(w10, kd, w11 * ke);   // x-coupling for beta

    // Preload this batch's entire x row: 8 regs, 64 steps each.
    const float* xrow = x + (size_t)b * Tc;
    float xr[CH];
#pragma unroll
    for (int c = 0; c < CH; ++c) xr[c] = xrow[lane + 64 * c];

    // Carried state: alpha = au*q1 + x*A1, beta = au*q2 + x*A2.
    float au = 1.0f;
    float q1 = fmaf(w00, s0d, w01 * s0e);
    float q2 = fmaf(w10, s0d, w11 * s0e);

#pragma unroll
    for (int c = 0; c < CH; ++c) {
        float obuf = 0.f;
#pragma unroll 2
        for (int t2 = 0; t2 < 64; ++t2) {
            const float xs = readlane_f(xr[c], t2);

            const float alpha = fmaf(au, q1, xs * A1);
            const float beta  = fmaf(au, q2, xs * A2);

            const float aun = copysignf(fmaxf(fabsf(alpha), 1e-20f), alpha);
            const float inv = __builtin_amdgcn_rcpf(aun);
            const float r   = beta * inv;
            const float bb  = fabsf(inv);
            const float nb  = -bb;
            const f32x2 r2  = {r, r};

            f32x2 a1a = {0.f, 0.f}, a1b = {0.f, 0.f};
            f32x2 a2a = {0.f, 0.f}, a2b = {0.f, 0.f};
            f32x2 aoa = {0.f, 0.f}, aob = {0.f, 0.f};
            ACC_J(0, a1a, a2a, aoa); ACC_J(1, a1b, a2b, aob);
            ACC_J(2, a1a, a2a, aoa); ACC_J(3, a1b, a2b, aob);
            ACC_J(4, a1a, a2a, aoa); ACC_J(5, a1b, a2b, aob);
            ACC_J(6, a1a, a2a, aoa); ACC_J(7, a1b, a2b, aob);

            const f32x2 s1v = a1a + a1b;
            const f32x2 s2v = a2a + a2b;
            const f32x2 sov = aoa + aob;
            float h1 = s1v.x + s1v.y;
            float h2 = s2v.x + s2v.y;
            float ho = sov.x + sov.y;

            float q1n, q2n, son;
            WAVE_REDUCE3_READ(h1, h2, ho, q1n, q2n, son);
            q1 = q1n;                       // = w00*sigma_d + w01*sigma_e
            q2 = q2n;
            au = aun;

            const float ov = aun * son;     // out_t = au * sigma_o
            obuf = (t2 == lane) ? ov : obuf;
        }
        out[(size_t)b * Tc + 64 * c + lane] = obuf;
    }
}

extern "C" void kernel_launch(void* const* d_in, const int* in_sizes, int n_in,
                              void* d_out, int out_size, void* d_ws, size_t ws_size,
                              hipStream_t stream) {
    const float* x        = (const float*)d_in[0];
    const float* state0   = (const float*)d_in[1];
    const float* mask     = (const float*)d_in[2];
    const float* w        = (const float*)d_in[3];
    const float* dec_orth = (const float*)d_in[4];
    const float* enc_orth = (const float*)d_in[5];
    const float* decoder  = (const float*)d_in[6];
    const float* encoder  = (const float*)d_in[7];
    float* out = (float*)d_out;

    twotwonet_kernel<<<dim3(Bc), dim3(64), 0, stream>>>(
        x, state0, mask, w, dec_orth, enc_orth, decoder, encoder, out);
}